// Round 15
// baseline (99327.820 us; speedup 1.0000x reference)
//
#include <hip/hip_runtime.h>

#define HH 1024
#define TT 4096
#define NWG 256
#define NWG_PER_LAYER 128
#define JS_PER_WG 8     // 1024 / 128
#define JS_PER_WAVE 2   // 8 j's / 4 waves
#define LDS_BYTES 131072  // 4 waves * 8 rows * 1024 floats * 4 B (w_hh tile)

__device__ __forceinline__ float fsigmoid(float x) {
    return 1.0f / (1.0f + __expf(-x));
}
__device__ __forceinline__ float ftanh(float x) {
    float ax = fabsf(x);
    float e = __expf(-2.0f * ax);
    float t = (1.0f - e) / (1.0f + e);
    return copysignf(t, x);
}
__device__ __forceinline__ void fma4(float& a, const float4 w, const float4 v) {
    a = fmaf(w.x, v.x, a);
    a = fmaf(w.y, v.y, a);
    a = fmaf(w.z, v.z, a);
    a = fmaf(w.w, v.w, a);
}

// ---- (value, epoch) pair ring primitives -------------------------------
// Pair = 8B {f32 value, u32 tag}. An 8B single-copy-atomic store publishes the
// value WITH its tag (same word -> tag-visible implies value-visible; no
// separate barrier or fence). Consumers poll the pairs directly: detection ==
// data delivery (1 LLC RT), replacing round-13's arrive-store -> slot-poll ->
// h-load chain (3 RTs). Round-14 lesson: 128-bit structs can't be inline-asm
// INPUTS (outputs are fine) -> producer side uses __hip_atomic_store.

__device__ __forceinline__ void publish_pair(void* base, int jbase,
                                             float h0, float h1, unsigned tag) {
    const unsigned long long w0 =
        ((unsigned long long)tag << 32) | (unsigned long long)__float_as_uint(h0);
    const unsigned long long w1 =
        ((unsigned long long)tag << 32) | (unsigned long long)__float_as_uint(h1);
    unsigned long long* p =
        (unsigned long long*)((char*)base + (size_t)jbase * 8);
    __hip_atomic_store(p,     w0, __ATOMIC_RELAXED, __HIP_MEMORY_SCOPE_AGENT);
    __hip_atomic_store(p + 1, w1, __ATOMIC_RELAXED, __HIP_MEMORY_SCOPE_AGENT);
}

// Spin until this lane's 16 pairs (elements 16l..16l+15) all carry `expect`;
// returns the values. 8 pipelined dwordx4 sc0/sc1 loads, one vmcnt.
__device__ __forceinline__ void poll_pairs(float4 v[4], const void* base,
                                           unsigned expect) {
    const char* p = (const char*)base + (size_t)(threadIdx.x & 63) * 128;
    for (;;) {
        uint4 a0, a1, a2, a3, a4, a5, a6, a7;
        asm volatile(
            "global_load_dwordx4 %0, %8, off sc0 sc1\n\t"
            "global_load_dwordx4 %1, %8, off offset:16 sc0 sc1\n\t"
            "global_load_dwordx4 %2, %8, off offset:32 sc0 sc1\n\t"
            "global_load_dwordx4 %3, %8, off offset:48 sc0 sc1\n\t"
            "global_load_dwordx4 %4, %8, off offset:64 sc0 sc1\n\t"
            "global_load_dwordx4 %5, %8, off offset:80 sc0 sc1\n\t"
            "global_load_dwordx4 %6, %8, off offset:96 sc0 sc1\n\t"
            "global_load_dwordx4 %7, %8, off offset:112 sc0 sc1\n\t"
            "s_waitcnt vmcnt(0)"
            : "=&v"(a0), "=&v"(a1), "=&v"(a2), "=&v"(a3),
              "=&v"(a4), "=&v"(a5), "=&v"(a6), "=&v"(a7)
            : "v"(p) : "memory");
        const bool ok =
            (a0.y == expect) & (a0.w == expect) & (a1.y == expect) & (a1.w == expect) &
            (a2.y == expect) & (a2.w == expect) & (a3.y == expect) & (a3.w == expect) &
            (a4.y == expect) & (a4.w == expect) & (a5.y == expect) & (a5.w == expect) &
            (a6.y == expect) & (a6.w == expect) & (a7.y == expect) & (a7.w == expect);
        if (__all((int)ok)) {
            v[0] = make_float4(__uint_as_float(a0.x), __uint_as_float(a0.z),
                               __uint_as_float(a1.x), __uint_as_float(a1.z));
            v[1] = make_float4(__uint_as_float(a2.x), __uint_as_float(a2.z),
                               __uint_as_float(a3.x), __uint_as_float(a3.z));
            v[2] = make_float4(__uint_as_float(a4.x), __uint_as_float(a4.z),
                               __uint_as_float(a5.x), __uint_as_float(a5.z));
            v[3] = make_float4(__uint_as_float(a6.x), __uint_as_float(a6.z),
                               __uint_as_float(a7.x), __uint_as_float(a7.z));
            return;
        }
        __builtin_amdgcn_s_sleep(1);
    }
}

// Lagged backpressure: all 1024 per-wave progress slots >= tgt (4 dwordx4 per
// lane = 16 slots; 64 lanes cover all 1024 in one RT). Ring depth 4, lag 2:
// almost never actually blocks -- only prevents >2-step wave spread.
__device__ __forceinline__ void poll_slots(const int* slots, int tgt) {
    const int* p = slots + 16 * (threadIdx.x & 63);
    for (;;) {
        int4 s0, s1, s2, s3;
        asm volatile(
            "global_load_dwordx4 %0, %4, off sc0 sc1\n\t"
            "global_load_dwordx4 %1, %4, off offset:16 sc0 sc1\n\t"
            "global_load_dwordx4 %2, %4, off offset:32 sc0 sc1\n\t"
            "global_load_dwordx4 %3, %4, off offset:48 sc0 sc1\n\t"
            "s_waitcnt vmcnt(0)"
            : "=&v"(s0), "=&v"(s1), "=&v"(s2), "=&v"(s3)
            : "v"(p) : "memory");
        int m = min(min(min(s0.x, s0.y), min(s0.z, s0.w)),
                    min(min(s1.x, s1.y), min(s1.z, s1.w)));
        m = min(m, min(min(min(s2.x, s2.y), min(s2.z, s2.w)),
                       min(min(s3.x, s3.y), min(s3.z, s3.w))));
        if (__all(m >= tgt)) return;
        __builtin_amdgcn_s_sleep(2);
    }
}

#define FOR_R(F) F(0) F(1) F(2) F(3) F(4) F(5) F(6) F(7)

// Persistent 2-layer LSTM, tag-fused dataflow (round-15 = round-14 + compile fix).
// WGs [0,128): layer 0 (t = k). WGs [128,256): layer 1 (t = k-2, skew 2).
// No in-loop __syncthreads, no grid barrier on the critical path: waves
// free-run, synchronized only by (value,tag) pair polls.
// Per wave per step: CRITICAL {poll own-recurrence pairs (1 RT, data arrives
// with detection) -> w_hh GEMV (LDS) -> reduce -> +bias -> gates -> publish
// (h,tag) pairs (2 x 8B atomic stores, fire-and-forget)} -> SLACK {gx[t+1] =
// w_ih @ input[t+1]; L1 polls h1[t+1] pairs} -> progress-slot store ->
// lagged backpressure poll.
//   w_hh: 128 KB LDS [wave][row][q][lane] (conflict-free ds_read_b128)
//   w_ih: streamed from global (L2-resident) every step, in slack
//   h1: pair ring R1[4][1024] (L0 publishes; L0 recurrence + L1 input)
//   h2: pair ring R2[4][1024] (L1 publishes; L1 recurrence) + plain out[t]
__global__ __launch_bounds__(256, 1) void lstm2_persistent(
    const float* __restrict__ x,
    const float* __restrict__ wih0, const float* __restrict__ whh0,
    const float* __restrict__ bih0, const float* __restrict__ bhh0,
    const float* __restrict__ wih1, const float* __restrict__ whh1,
    const float* __restrict__ bih1, const float* __restrict__ bhh1,
    float* __restrict__ out,     // [T][H] h2 (plain output)
    char* __restrict__ r1,       // R1 pair ring, 4 * 8192 B
    char* __restrict__ r2,       // R2 pair ring, 4 * 8192 B
    int*  __restrict__ slotsw)   // 1024 per-wave progress slots (zeroed)
{
    extern __shared__ float ldsw[];   // w_hh tile, 128 KB

    const int wg   = blockIdx.x;
    const int tid  = threadIdx.x;
    const int wave = tid >> 6;
    const int lane = tid & 63;
    const bool isL1 = (wg >= NWG_PER_LAYER);
    const int wgl   = isL1 ? (wg - NWG_PER_LAYER) : wg;
    const int jbase = wgl * JS_PER_WG + wave * JS_PER_WAVE;
    const int col   = lane * 16;   // this lane's 16-elem chunk of the 1024-vector
    const int gwave = wg * 4 + wave;

    const float* wih = isL1 ? wih1 : wih0;
    const float* whh = isL1 ? whh1 : whh0;
    const float* bih = isL1 ? bih1 : bih0;
    const float* bhh = isL1 ? bhh1 : bhh0;
    char* rrec = isL1 ? r2 : r1;   // ring this layer's recurrence reads/writes

    // ---- stage w_hh into LDS: float offset = wave*8192 + r*1024 + q*256 + lane*4
    #pragma unroll
    for (int r = 0; r < 8; ++r) {
        const int row = (r & 3) * HH + (jbase + (r >> 2));
        const float4* p  = (const float4*)(whh + (size_t)row * HH + col);
        float*       wb = ldsw + wave * 8192 + r * 1024 + lane * 4;
        #pragma unroll
        for (int q = 0; q < 4; ++q)
            *(float4*)(wb + q * 256) = p[q];
    }

    // ---- bias (applied AFTER the butterfly reduce, uniform across lanes) ----
    #define DECLB(r) float B##r; { const int row = ((r)&3)*HH + (jbase + ((r)>>2)); \
                                   B##r = bih[row] + bhh[row]; }
    FOR_R(DECLB)

    // gx per-lane partials, carried in registers across the step boundary
    #define DECLG(r) float gxp##r = 0.0f;
    FOR_R(DECLG)

    float c0v = 0.0f, c1v = 0.0f;
    int loff  = wave * 8192 + lane * 4;  // LDS float offset (pinned per iter)
    int wioff = 0;                       // global w_ih offset (pinned per iter)

    // streamed input-GEMV partial: gxp_r = w_ih[rows(r)][col..col+16) @ iv
    #define GXR(r) { \
        const int row = ((r) & 3) * HH + (jbase + ((r) >> 2)); \
        const float4* wp = (const float4*)(wih + (size_t)row * HH + col + wioff); \
        float4 w0 = wp[0], w1 = wp[1], w2 = wp[2], w3 = wp[3]; \
        float a = 0.0f; \
        fma4(a, w0, iv4[0]); fma4(a, w1, iv4[1]); \
        fma4(a, w2, iv4[2]); fma4(a, w3, iv4[3]); \
        gxp##r = a; }

    // ---- prologue: L0 needs gx[0] before the first step ----
    if (!isL1) {
        float4 iv4[4];
        const float4* p = (const float4*)(x + col);
        iv4[0] = p[0]; iv4[1] = p[1]; iv4[2] = p[2]; iv4[3] = p[3];
        FOR_R(GXR)
    }

    __syncthreads();   // LDS w_hh tile ready (only barrier in the kernel)

    for (int k = 0; k <= TT + 1; ++k) {
        asm volatile("" : "+v"(loff), "+v"(wioff));

        const int t = isL1 ? (k - 2) : k;

        // ================= CRITICAL phase =================
        if (t >= 0 && t < TT) {
            float4 hp4[4];
            if (t > 0) {
                // poll own-layer recurrence pairs: h[t-1], tag t
                poll_pairs(hp4, rrec + (size_t)((t - 1) & 3) * 8192, (unsigned)t);
            } else {
                hp4[0] = hp4[1] = hp4[2] = hp4[3] = make_float4(0.f, 0.f, 0.f, 0.f);
            }

            float acc0, acc1, acc2, acc3, acc4, acc5, acc6, acc7;
            #define DOTW(r) { float a = gxp##r; \
                const float4* wp = (const float4*)(ldsw + loff + (r) * 1024); \
                fma4(a, wp[0],   hp4[0]); fma4(a, wp[64],  hp4[1]); \
                fma4(a, wp[128], hp4[2]); fma4(a, wp[192], hp4[3]); \
                acc##r = a; }
            FOR_R(DOTW)

            #define REDW(m) \
                acc0 += __shfl_xor(acc0, m, 64); acc1 += __shfl_xor(acc1, m, 64); \
                acc2 += __shfl_xor(acc2, m, 64); acc3 += __shfl_xor(acc3, m, 64); \
                acc4 += __shfl_xor(acc4, m, 64); acc5 += __shfl_xor(acc5, m, 64); \
                acc6 += __shfl_xor(acc6, m, 64); acc7 += __shfl_xor(acc7, m, 64);
            REDW(1) REDW(2) REDW(4) REDW(8) REDW(16) REDW(32)

            // gates (PyTorch order i,f,g,o); bias added post-reduce
            const float gi0 = fsigmoid(acc0 + B0), gf0 = fsigmoid(acc1 + B1);
            const float gg0 = ftanh(acc2 + B2),    go0 = fsigmoid(acc3 + B3);
            c0v = gf0 * c0v + gi0 * gg0;
            const float h0 = go0 * ftanh(c0v);
            const float gi1 = fsigmoid(acc4 + B4), gf1 = fsigmoid(acc5 + B5);
            const float gg1 = ftanh(acc6 + B6),    go1 = fsigmoid(acc7 + B7);
            c1v = gf1 * c1v + gi1 * gg1;
            const float h1v = go1 * ftanh(c1v);

            if (lane == 0) {
                // publish (h, tag=t+1) pairs -- tag travels WITH the data
                publish_pair(rrec + (size_t)(t & 3) * 8192, jbase, h0, h1v,
                             (unsigned)(t + 1));
                if (isL1)   // plain output store (recurrence uses R2, not out)
                    *(float2*)(out + (size_t)t * HH + jbase) = make_float2(h0, h1v);
            }
        }

        // ================= SLACK phase: gx for next timestep =================
        {
            const int tn = t + 1;
            if (tn >= 0 && tn < TT) {
                float4 iv4[4];
                if (!isL1) {
                    const float4* p = (const float4*)(x + (size_t)tn * HH + col);
                    iv4[0] = p[0]; iv4[1] = p[1]; iv4[2] = p[2]; iv4[3] = p[3];
                } else {
                    // h1[tn] pairs, tag tn+1 (L0 publishes these at step tn)
                    poll_pairs(iv4, r1 + (size_t)(tn & 3) * 8192, (unsigned)(tn + 1));
                }
                FOR_R(GXR)
            }
        }
        asm volatile("" : "+v"(gxp0), "+v"(gxp1), "+v"(gxp2), "+v"(gxp3),
                         "+v"(gxp4), "+v"(gxp5), "+v"(gxp6), "+v"(gxp7));

        // ============ progress slot + lagged backpressure ============
        // slot = k+1 (completed step k, incl. slack reads of epoch k-1 data).
        // Wait all waves >= k-1 (completed k-2) BEFORE step k+1's publish
        // overwrites epoch k-3 pairs. Lag 2 -> rarely blocks.
        if (lane == 0)
            __hip_atomic_store(&slotsw[gwave], k + 1,
                               __ATOMIC_RELAXED, __HIP_MEMORY_SCOPE_AGENT);
        poll_slots(slotsw, k - 1);
    }
}

extern "C" void kernel_launch(void* const* d_in, const int* in_sizes, int n_in,
                              void* d_out, int out_size, void* d_ws, size_t ws_size,
                              hipStream_t stream) {
    (void)in_sizes; (void)n_in; (void)out_size; (void)ws_size;
    const float* x    = (const float*)d_in[0];
    const float* wih0 = (const float*)d_in[1];
    const float* whh0 = (const float*)d_in[2];
    const float* bih0 = (const float*)d_in[3];
    const float* bhh0 = (const float*)d_in[4];
    const float* wih1 = (const float*)d_in[5];
    const float* whh1 = (const float*)d_in[6];
    const float* bih1 = (const float*)d_in[7];
    const float* bhh1 = (const float*)d_in[8];
    float* out = (float*)d_out;

    // ws layout: [0,4096) slotsw (1024 x 4B) | [4096,36864) R1 pair ring |
    //            [36864,69632) R2 pair ring
    int*  slotsw = (int*)d_ws;
    char* r1     = (char*)d_ws + 4096;
    char* r2     = (char*)d_ws + 36864;

    // allow 128 KB dynamic LDS (160 KB available per CU on gfx950)
    (void)hipFuncSetAttribute((const void*)lstm2_persistent,
                              hipFuncAttributeMaxDynamicSharedMemorySize, LDS_BYTES);

    // zero slots + both pair rings every call (also clears stale tags from
    // the previous replay -- required, harness does not re-poison d_ws)
    (void)hipMemsetAsync(d_ws, 0, 69632, stream);

    hipLaunchKernelGGL(lstm2_persistent, dim3(NWG), dim3(256), LDS_BYTES, stream,
                       x, wih0, whh0, bih0, bhh0,
                       wih1, whh1, bih1, bhh1, out, r1, r2, slotsw);
}

// Round 16
// 29519.110 us; speedup vs baseline: 3.3649x; 3.3649x over previous
//
#include <hip/hip_runtime.h>

#define HH 1024
#define TT 4096
#define NWG 256
#define NWG_PER_LAYER 128
#define JS_PER_WG 8     // 1024 / 128
#define JS_PER_WAVE 2   // 8 j's / 4 waves
#define LDS_BYTES 131072  // 4 waves * 8 rows * 1024 floats * 4 B (w_hh tile)

__device__ __forceinline__ float fsigmoid(float x) {
    return 1.0f / (1.0f + __expf(-x));
}
__device__ __forceinline__ float ftanh(float x) {
    float ax = fabsf(x);
    float e = __expf(-2.0f * ax);
    float t = (1.0f - e) / (1.0f + e);
    return copysignf(t, x);
}
__device__ __forceinline__ void fma4(float& a, const float4 w, const float4 v) {
    a = fmaf(w.x, v.x, a);
    a = fmaf(w.y, v.y, a);
    a = fmaf(w.z, v.z, a);
    a = fmaf(w.w, v.w, a);
}

// ---- (value, epoch) pair primitives ------------------------------------
// Pair = 8B {f32 value, u32 tag}; 8B single-copy-atomic store publishes value
// WITH tag. Producer side: __hip_atomic_store (r14 lesson: 128-bit structs
// can't be inline-asm inputs).
__device__ __forceinline__ void publish_pair(void* base, int jbase,
                                             float h0, float h1, unsigned tag) {
    const unsigned long long w0 =
        ((unsigned long long)tag << 32) | (unsigned long long)__float_as_uint(h0);
    const unsigned long long w1 =
        ((unsigned long long)tag << 32) | (unsigned long long)__float_as_uint(h1);
    unsigned long long* p =
        (unsigned long long*)((char*)base + (size_t)jbase * 8);
    __hip_atomic_store(p,     w0, __ATOMIC_RELAXED, __HIP_MEMORY_SCOPE_AGENT);
    __hip_atomic_store(p + 1, w1, __ATOMIC_RELAXED, __HIP_MEMORY_SCOPE_AGENT);
}

#define PAIR_UNPACK(v, a0,a1,a2,a3,a4,a5,a6,a7) \
    v[0] = make_float4(__uint_as_float(a0.x), __uint_as_float(a0.z), \
                       __uint_as_float(a1.x), __uint_as_float(a1.z)); \
    v[1] = make_float4(__uint_as_float(a2.x), __uint_as_float(a2.z), \
                       __uint_as_float(a3.x), __uint_as_float(a3.z)); \
    v[2] = make_float4(__uint_as_float(a4.x), __uint_as_float(a4.z), \
                       __uint_as_float(a5.x), __uint_as_float(a5.z)); \
    v[3] = make_float4(__uint_as_float(a6.x), __uint_as_float(a6.z), \
                       __uint_as_float(a7.x), __uint_as_float(a7.z));

#define TAGS_OK(e, a0,a1,a2,a3,a4,a5,a6,a7) \
    ((a0.y==e)&(a0.w==e)&(a1.y==e)&(a1.w==e)&(a2.y==e)&(a2.w==e)& \
     (a3.y==e)&(a3.w==e)&(a4.y==e)&(a4.w==e)&(a5.y==e)&(a5.w==e)& \
     (a6.y==e)&(a6.w==e)&(a7.y==e)&(a7.w==e))

// Slack-phase pair read (data guaranteed published by the previous barrier;
// loop is a safety net, expected to exit on attempt 1).
__device__ __forceinline__ void poll_pairs(float4 v[4], const void* base,
                                           unsigned expect) {
    const char* p = (const char*)base + (size_t)(threadIdx.x & 63) * 128;
    for (;;) {
        uint4 a0, a1, a2, a3, a4, a5, a6, a7;
        asm volatile(
            "global_load_dwordx4 %0, %8, off sc0 sc1\n\t"
            "global_load_dwordx4 %1, %8, off offset:16 sc0 sc1\n\t"
            "global_load_dwordx4 %2, %8, off offset:32 sc0 sc1\n\t"
            "global_load_dwordx4 %3, %8, off offset:48 sc0 sc1\n\t"
            "global_load_dwordx4 %4, %8, off offset:64 sc0 sc1\n\t"
            "global_load_dwordx4 %5, %8, off offset:80 sc0 sc1\n\t"
            "global_load_dwordx4 %6, %8, off offset:96 sc0 sc1\n\t"
            "global_load_dwordx4 %7, %8, off offset:112 sc0 sc1\n\t"
            "s_waitcnt vmcnt(0)"
            : "=&v"(a0), "=&v"(a1), "=&v"(a2), "=&v"(a3),
              "=&v"(a4), "=&v"(a5), "=&v"(a6), "=&v"(a7)
            : "v"(p) : "memory");
        const bool ok = TAGS_OK(expect, a0,a1,a2,a3,a4,a5,a6,a7);
        if (__all((int)ok)) { PAIR_UNPACK(v, a0,a1,a2,a3,a4,a5,a6,a7); return; }
        __builtin_amdgcn_s_sleep(1);
    }
}

// r13-proven slot barrier (slots-only poll, 16B/lane/attempt).
__device__ __forceinline__ void slot_barrier_wait(const unsigned* slots, unsigned tgt) {
    const unsigned* p = slots + 4 * (threadIdx.x & 63);
    for (;;) {
        uint4 v;
        asm volatile(
            "global_load_dwordx4 %0, %1, off sc0 sc1\n\t"
            "s_waitcnt vmcnt(0)"
            : "=&v"(v) : "v"(p) : "memory");
        const unsigned m = min(min(v.x, v.y), min(v.z, v.w));
        if (__all(m >= tgt)) break;
        __builtin_amdgcn_s_sleep(1);
    }
}

// Fused speculative poll: one batch loads slots (16B/lane) AND next-step
// recurrence pairs (128B/lane). Exits when all 256 slots >= tgt and all 16
// tags == expect -- the detection attempt itself delivers the h data,
// removing the separate post-barrier h-load RT from the critical chain.
// Attempts are bounded by the hard barrier (no r15-style free-run storm).
__device__ __forceinline__ void poll_fused(const unsigned* slots, unsigned tgt,
                                           const void* pbase, unsigned expect,
                                           float4 v[4]) {
    const int lane = threadIdx.x & 63;
    const unsigned* sp = slots + 4 * lane;
    const char* p = (const char*)pbase + (size_t)lane * 128;
    for (;;) {
        uint4 s, a0, a1, a2, a3, a4, a5, a6, a7;
        asm volatile(
            "global_load_dwordx4 %0, %9, off sc0 sc1\n\t"
            "global_load_dwordx4 %1, %10, off sc0 sc1\n\t"
            "global_load_dwordx4 %2, %10, off offset:16 sc0 sc1\n\t"
            "global_load_dwordx4 %3, %10, off offset:32 sc0 sc1\n\t"
            "global_load_dwordx4 %4, %10, off offset:48 sc0 sc1\n\t"
            "global_load_dwordx4 %5, %10, off offset:64 sc0 sc1\n\t"
            "global_load_dwordx4 %6, %10, off offset:80 sc0 sc1\n\t"
            "global_load_dwordx4 %7, %10, off offset:96 sc0 sc1\n\t"
            "global_load_dwordx4 %8, %10, off offset:112 sc0 sc1\n\t"
            "s_waitcnt vmcnt(0)"
            : "=&v"(s), "=&v"(a0), "=&v"(a1), "=&v"(a2), "=&v"(a3),
              "=&v"(a4), "=&v"(a5), "=&v"(a6), "=&v"(a7)
            : "v"(sp), "v"(p) : "memory");
        const unsigned m = min(min(s.x, s.y), min(s.z, s.w));
        const bool ok = (m >= tgt) & TAGS_OK(expect, a0,a1,a2,a3,a4,a5,a6,a7);
        if (__all((int)ok)) { PAIR_UNPACK(v, a0,a1,a2,a3,a4,a5,a6,a7); return; }
        __builtin_amdgcn_s_sleep(1);
    }
}

#define FOR_R(F) F(0) F(1) F(2) F(3) F(4) F(5) F(6) F(7)

// Persistent 2-layer LSTM = round-13 skeleton + fused speculative poll.
// WGs [0,128): layer 0 (t = k). WGs [128,256): layer 1 (t = k-2, skew 2).
// Per step: CRITICAL {w_hh GEMV on pre-fetched hp4 -> reduce -> +bias ->
// gates -> publish (h,tag) pairs (+plain out for L1)} -> syncthreads ->
// ARRIVE (tid0: slot[wg]=k+1) -> SLACK {gx[t+1]; L1 reads h1[tn] pairs,
// 1st-attempt} -> FUSED POLL {slots>=k+1 AND next-recurrence pairs tagged;
// exit delivers hp4 for the next step}.
//   w_hh: 128 KB LDS [wave][row][q][lane] (conflict-free ds_read_b128)
//   w_ih: streamed from global (L2-resident) every step, in slack
//   h1: pair ring R1[4][1024] (L0 publishes); h2: pair ring R2[4][1024]
//   (L1 publishes; `out` is write-only)
__global__ __launch_bounds__(256, 1) void lstm2_persistent(
    const float* __restrict__ x,
    const float* __restrict__ wih0, const float* __restrict__ whh0,
    const float* __restrict__ bih0, const float* __restrict__ bhh0,
    const float* __restrict__ wih1, const float* __restrict__ whh1,
    const float* __restrict__ bih1, const float* __restrict__ bhh1,
    float* __restrict__ out,     // [T][H] h2 (plain output, write-only)
    char* __restrict__ r1,       // R1 pair ring, 4 * 8192 B
    char* __restrict__ r2,       // R2 pair ring, 4 * 8192 B
    unsigned* __restrict__ slots)     // 256 per-WG epoch slots (zeroed)
{
    extern __shared__ float ldsw[];   // w_hh tile, 128 KB

    const int wg   = blockIdx.x;
    const int tid  = threadIdx.x;
    const int wave = tid >> 6;
    const int lane = tid & 63;
    const bool isL1 = (wg >= NWG_PER_LAYER);
    const int wgl   = isL1 ? (wg - NWG_PER_LAYER) : wg;
    const int jbase = wgl * JS_PER_WG + wave * JS_PER_WAVE;
    const int col   = lane * 16;   // this lane's 16-elem chunk of the 1024-vector

    const float* wih = isL1 ? wih1 : wih0;
    const float* whh = isL1 ? whh1 : whh0;
    const float* bih = isL1 ? bih1 : bih0;
    const float* bhh = isL1 ? bhh1 : bhh0;
    char* rrec = isL1 ? r2 : r1;   // ring this layer's recurrence reads/writes

    // ---- stage w_hh into LDS: float offset = wave*8192 + r*1024 + q*256 + lane*4
    #pragma unroll
    for (int r = 0; r < 8; ++r) {
        const int row = (r & 3) * HH + (jbase + (r >> 2));
        const float4* p  = (const float4*)(whh + (size_t)row * HH + col);
        float*       wb = ldsw + wave * 8192 + r * 1024 + lane * 4;
        #pragma unroll
        for (int q = 0; q < 4; ++q)
            *(float4*)(wb + q * 256) = p[q];
    }

    // ---- bias (applied AFTER the butterfly reduce, uniform across lanes) ----
    #define DECLB(r) float B##r; { const int row = ((r)&3)*HH + (jbase + ((r)>>2)); \
                                   B##r = bih[row] + bhh[row]; }
    FOR_R(DECLB)

    // gx per-lane partials, carried in registers across the step boundary
    #define DECLG(r) float gxp##r = 0.0f;
    FOR_R(DECLG)

    float c0v = 0.0f, c1v = 0.0f;
    int loff  = wave * 8192 + lane * 4;  // LDS float offset (pinned per iter)
    int wioff = 0;                       // global w_ih offset (pinned per iter)

    // recurrence h for the upcoming critical phase (pre-fetched by the poll)
    float4 hp4[4];
    hp4[0] = hp4[1] = hp4[2] = hp4[3] = make_float4(0.f, 0.f, 0.f, 0.f);

    // streamed input-GEMV partial: gxp_r = w_ih[rows(r)][col..col+16) @ iv
    #define GXR(r) { \
        const int row = ((r) & 3) * HH + (jbase + ((r) >> 2)); \
        const float4* wp = (const float4*)(wih + (size_t)row * HH + col + wioff); \
        float4 w0 = wp[0], w1 = wp[1], w2 = wp[2], w3 = wp[3]; \
        float a = 0.0f; \
        fma4(a, w0, iv4[0]); fma4(a, w1, iv4[1]); \
        fma4(a, w2, iv4[2]); fma4(a, w3, iv4[3]); \
        gxp##r = a; }

    // ---- prologue: L0 needs gx[0] before the first step ----
    if (!isL1) {
        float4 iv4[4];
        const float4* p = (const float4*)(x + col);
        iv4[0] = p[0]; iv4[1] = p[1]; iv4[2] = p[2]; iv4[3] = p[3];
        FOR_R(GXR)
    }

    __syncthreads();   // LDS w_hh tile ready

    for (int k = 0; k <= TT + 1; ++k) {
        asm volatile("" : "+v"(loff), "+v"(wioff));

        const int t = isL1 ? (k - 2) : k;

        // ================= CRITICAL phase (h pre-fetched into hp4) ==========
        if (t >= 0 && t < TT) {
            float acc0, acc1, acc2, acc3, acc4, acc5, acc6, acc7;
            #define DOTW(r) { float a = gxp##r; \
                const float4* wp = (const float4*)(ldsw + loff + (r) * 1024); \
                fma4(a, wp[0],   hp4[0]); fma4(a, wp[64],  hp4[1]); \
                fma4(a, wp[128], hp4[2]); fma4(a, wp[192], hp4[3]); \
                acc##r = a; }
            FOR_R(DOTW)

            #define REDW(m) \
                acc0 += __shfl_xor(acc0, m, 64); acc1 += __shfl_xor(acc1, m, 64); \
                acc2 += __shfl_xor(acc2, m, 64); acc3 += __shfl_xor(acc3, m, 64); \
                acc4 += __shfl_xor(acc4, m, 64); acc5 += __shfl_xor(acc5, m, 64); \
                acc6 += __shfl_xor(acc6, m, 64); acc7 += __shfl_xor(acc7, m, 64);
            REDW(1) REDW(2) REDW(4) REDW(8) REDW(16) REDW(32)

            // gates (PyTorch order i,f,g,o); bias added post-reduce
            const float gi0 = fsigmoid(acc0 + B0), gf0 = fsigmoid(acc1 + B1);
            const float gg0 = ftanh(acc2 + B2),    go0 = fsigmoid(acc3 + B3);
            c0v = gf0 * c0v + gi0 * gg0;
            const float h0 = go0 * ftanh(c0v);
            const float gi1 = fsigmoid(acc4 + B4), gf1 = fsigmoid(acc5 + B5);
            const float gg1 = ftanh(acc6 + B6),    go1 = fsigmoid(acc7 + B7);
            c1v = gf1 * c1v + gi1 * gg1;
            const float h1v = go1 * ftanh(c1v);

            if (lane == 0) {
                publish_pair(rrec + (size_t)(t & 3) * 8192, jbase, h0, h1v,
                             (unsigned)(t + 1));
                if (isL1)   // plain output store (recurrence reads R2, not out)
                    *(float2*)(out + (size_t)t * HH + jbase) = make_float2(h0, h1v);
            }
        }

        __syncthreads();   // all 4 waves drain their publishes (vmcnt before s_barrier)

        if (k <= TT) {
            // ================= ARRIVE: plain per-WG epoch store ==============
            if (tid == 0) {
                asm volatile("s_waitcnt vmcnt(0)" ::: "memory");
                __hip_atomic_store(&slots[wg], (unsigned)(k + 1),
                                   __ATOMIC_RELAXED, __HIP_MEMORY_SCOPE_AGENT);
            }

            // ================= SLACK: gx for next timestep ===================
            {
                const int tn = t + 1;
                if (tn >= 0 && tn < TT) {
                    float4 iv4[4];
                    if (!isL1) {
                        const float4* p = (const float4*)(x + (size_t)tn * HH + col);
                        iv4[0] = p[0]; iv4[1] = p[1]; iv4[2] = p[2]; iv4[3] = p[3];
                    } else {
                        // h1[tn] pairs, tag tn+1; published at L0 step tn,
                        // guaranteed by the PREVIOUS barrier -> 1st attempt
                        poll_pairs(iv4, r1 + (size_t)(tn & 3) * 8192,
                                   (unsigned)(tn + 1));
                    }
                    FOR_R(GXR)
                }
            }
            asm volatile("" : "+v"(gxp0), "+v"(gxp1), "+v"(gxp2), "+v"(gxp3),
                             "+v"(gxp4), "+v"(gxp5), "+v"(gxp6), "+v"(gxp7));

            // ====== FUSED POLL: barrier detect + next-step h delivery ========
            const unsigned tgt = (unsigned)(k + 1);
            const int tnext = isL1 ? (k - 1) : (k + 1);   // next step's t
            if (tnext > 0 && tnext < TT) {
                // recurrence h[tnext-1], published with tag tnext
                poll_fused(slots, tgt,
                           rrec + (size_t)((tnext - 1) & 3) * 8192,
                           (unsigned)tnext, hp4);
            } else {
                slot_barrier_wait(slots, tgt);
                hp4[0] = hp4[1] = hp4[2] = hp4[3] = make_float4(0.f, 0.f, 0.f, 0.f);
            }
        }
    }
}

extern "C" void kernel_launch(void* const* d_in, const int* in_sizes, int n_in,
                              void* d_out, int out_size, void* d_ws, size_t ws_size,
                              hipStream_t stream) {
    (void)in_sizes; (void)n_in; (void)out_size; (void)ws_size;
    const float* x    = (const float*)d_in[0];
    const float* wih0 = (const float*)d_in[1];
    const float* whh0 = (const float*)d_in[2];
    const float* bih0 = (const float*)d_in[3];
    const float* bhh0 = (const float*)d_in[4];
    const float* wih1 = (const float*)d_in[5];
    const float* whh1 = (const float*)d_in[6];
    const float* bih1 = (const float*)d_in[7];
    const float* bhh1 = (const float*)d_in[8];
    float* out = (float*)d_out;

    // ws layout: [0,1024) slots (256 x 4B) | [4096,36864) R1 pair ring |
    //            [36864,69632) R2 pair ring
    unsigned* slots = (unsigned*)d_ws;
    char*     r1    = (char*)d_ws + 4096;
    char*     r2    = (char*)d_ws + 36864;

    // allow 128 KB dynamic LDS (160 KB available per CU on gfx950)
    (void)hipFuncSetAttribute((const void*)lstm2_persistent,
                              hipFuncAttributeMaxDynamicSharedMemorySize, LDS_BYTES);

    // zero slots + both pair rings every call (clears stale tags between
    // replays -- harness does not re-poison d_ws)
    (void)hipMemsetAsync(d_ws, 0, 69632, stream);

    hipLaunchKernelGGL(lstm2_persistent, dim3(NWG), dim3(256), LDS_BYTES, stream,
                       x, wih0, whh0, bih0, bhh0,
                       wih1, whh1, bih1, bhh1, out, r1, r2, slots);
}

// Round 17
// 19684.851 us; speedup vs baseline: 5.0459x; 1.4996x over previous
//
#include <hip/hip_runtime.h>

#define HH 1024
#define TT 4096
#define NWG 256
#define NWG_PER_LAYER 128
#define JS_PER_WG 8     // 1024 / 128
#define JS_PER_WAVE 2   // 8 j's / 4 waves
#define LDS_BYTES 131072  // 4 waves * 8 rows * 1024 floats * 4 B (w_hh tile)

__device__ __forceinline__ float fsigmoid(float x) {
    return 1.0f / (1.0f + __expf(-x));
}
__device__ __forceinline__ float ftanh(float x) {
    float ax = fabsf(x);
    float e = __expf(-2.0f * ax);
    float t = (1.0f - e) / (1.0f + e);
    return copysignf(t, x);
}
__device__ __forceinline__ void fma4(float& a, const float4 w, const float4 v) {
    a = fmaf(w.x, v.x, a);
    a = fmaf(w.y, v.y, a);
    a = fmaf(w.z, v.z, a);
    a = fmaf(w.w, v.w, a);
}

// LLC-coherent 64B load, ONE round-trip (round-11 proven).
__device__ __forceinline__ void load64B_llc(float4 v[4], const float* p) {
    asm volatile(
        "global_load_dwordx4 %0, %4, off sc0 sc1\n\t"
        "global_load_dwordx4 %1, %4, off offset:16 sc0 sc1\n\t"
        "global_load_dwordx4 %2, %4, off offset:32 sc0 sc1\n\t"
        "global_load_dwordx4 %3, %4, off offset:48 sc0 sc1\n\t"
        "s_waitcnt vmcnt(0)"
        : "=&v"(v[0]), "=&v"(v[1]), "=&v"(v[2]), "=&v"(v[3])
        : "v"(p)
        : "memory");
}

// Thin slot-barrier poll with PER-LAYER thresholds. Lane l reads slots
// [4l..4l+3] (16B) with one dwordx4 sc0 sc1 -- 64 lanes = all 256 slots =
// one LLC RT per attempt. Lanes 0-31 cover L0's slots (0-127) and check
// tgt0; lanes 32-63 cover L1's slots (128-255) and check tgt1.
// r15/r16 law: poll attempts must stay thin (<=16B/lane); data loads are
// issued once, after detect.
__device__ __forceinline__ void slot_barrier_wait2(const unsigned* slots,
                                                   unsigned tgt0, unsigned tgt1) {
    const int lane = threadIdx.x & 63;
    const unsigned* p = slots + 4 * lane;
    const unsigned tgt = (lane < 32) ? tgt0 : tgt1;
    for (;;) {
        uint4 v;
        asm volatile(
            "global_load_dwordx4 %0, %1, off sc0 sc1\n\t"
            "s_waitcnt vmcnt(0)"
            : "=&v"(v) : "v"(p) : "memory");
        const unsigned m = min(min(v.x, v.y), min(v.z, v.w));
        if (__all(m >= tgt)) break;
        __builtin_amdgcn_s_sleep(1);
    }
}

#define FOR_R(F) F(0) F(1) F(2) F(3) F(4) F(5) F(6) F(7)

// Persistent 2-layer LSTM = round-13 skeleton + per-layer decoupled barrier.
// WGs [0,128): layer 0 (t = k). WGs [128,256): layer 1 (t = k-2, skew 2).
// Per step: CRITICAL {1-RT h load -> w_hh GEMV (LDS) -> reduce -> +bias ->
// gates -> store h} -> syncthreads -> ARRIVE (tid0: slot[wg]=k+1) ->
// SLACK {gx[t+1] = w_ih @ input[t+1]} -> POLL (thin, per-layer thresholds):
//   L0: slots_L0 >= k+1  &&  slots_L1 >= k-4   (h1 ring depth 8 => lag 5 safe;
//       audited: L1's slack read of h1[k-7] is covered by arrive(k-5)=k-4)
//   L1: slots_L0 >= k+1  &&  slots_L1 >= k+1   (consumes L0's latest h1)
// Steady state: L0 runs ahead; both layers then wait only on their OWN 128
// WGs -- halved barrier population, decoupled jitter (r12's race is fixed by
// depth-8 ring + the k-4 bound which covers slack-phase reads).
//   w_hh: 128 KB LDS [wave][row][q][lane] (conflict-free ds_read_b128)
//   w_ih: streamed from global (L2-resident) every step, in slack
//   h1: plain ring [8][1024]; h2 recurrence reads `out` directly.
__global__ __launch_bounds__(256, 1) void lstm2_persistent(
    const float* __restrict__ x,
    const float* __restrict__ wih0, const float* __restrict__ whh0,
    const float* __restrict__ bih0, const float* __restrict__ bhh0,
    const float* __restrict__ wih1, const float* __restrict__ whh1,
    const float* __restrict__ bih1, const float* __restrict__ bhh1,
    float* __restrict__ out,     // [T][H]  h2 (output + h2 recurrence buffer)
    float* __restrict__ ring,    // [8][H]  h1 ring (layer0 <-> layer1)
    const float* __restrict__ zbuf,   // [H] zeros (h[-1])
    unsigned* __restrict__ slots)     // 256 per-WG epoch slots (zeroed)
{
    extern __shared__ float ldsw[];   // w_hh tile, 128 KB

    const int wg   = blockIdx.x;
    const int tid  = threadIdx.x;
    const int wave = tid >> 6;
    const int lane = tid & 63;
    const bool isL1 = (wg >= NWG_PER_LAYER);
    const int wgl   = isL1 ? (wg - NWG_PER_LAYER) : wg;
    const int jbase = wgl * JS_PER_WG + wave * JS_PER_WAVE;
    const int col   = lane * 16;   // this lane's 16-elem chunk of the 1024-vector

    const float* wih = isL1 ? wih1 : wih0;
    const float* whh = isL1 ? whh1 : whh0;
    const float* bih = isL1 ? bih1 : bih0;
    const float* bhh = isL1 ? bhh1 : bhh0;

    // ---- stage w_hh into LDS: float offset = wave*8192 + r*1024 + q*256 + lane*4
    #pragma unroll
    for (int r = 0; r < 8; ++r) {
        const int row = (r & 3) * HH + (jbase + (r >> 2));
        const float4* p  = (const float4*)(whh + (size_t)row * HH + col);
        float*       wb = ldsw + wave * 8192 + r * 1024 + lane * 4;
        #pragma unroll
        for (int q = 0; q < 4; ++q)
            *(float4*)(wb + q * 256) = p[q];
    }

    // ---- bias (applied AFTER the butterfly reduce, uniform across lanes) ----
    #define DECLB(r) float B##r; { const int row = ((r)&3)*HH + (jbase + ((r)>>2)); \
                                   B##r = bih[row] + bhh[row]; }
    FOR_R(DECLB)

    // gx per-lane partials, carried in registers across the step boundary
    #define DECLG(r) float gxp##r = 0.0f;
    FOR_R(DECLG)

    float c0v = 0.0f, c1v = 0.0f;
    int loff  = wave * 8192 + lane * 4;  // LDS float offset (pinned per iter)
    int wioff = 0;                       // global w_ih offset (pinned per iter)

    // streamed input-GEMV partial: gxp_r = w_ih[rows(r)][col..col+16) @ iv
    // (NO bias here -- per-lane partials get summed 64x by the reduce)
    #define GXR(r) { \
        const int row = ((r) & 3) * HH + (jbase + ((r) >> 2)); \
        const float4* wp = (const float4*)(wih + (size_t)row * HH + col + wioff); \
        float4 w0 = wp[0], w1 = wp[1], w2 = wp[2], w3 = wp[3]; \
        float a = 0.0f; \
        fma4(a, w0, iv4[0]); fma4(a, w1, iv4[1]); \
        fma4(a, w2, iv4[2]); fma4(a, w3, iv4[3]); \
        gxp##r = a; }

    // ---- prologue: L0 needs gx[0] before the first step ----
    if (!isL1) {
        float4 iv4[4];
        const float4* p = (const float4*)(x + col);
        iv4[0] = p[0]; iv4[1] = p[1]; iv4[2] = p[2]; iv4[3] = p[3];
        FOR_R(GXR)
    }

    __syncthreads();   // LDS w_hh tile ready

    for (int k = 0; k <= TT + 1; ++k) {
        // per-iteration pins: block LICM of the (address-invariant) LDS w_hh
        // reads and global w_ih loads into spillable long-lived registers
        asm volatile("" : "+v"(loff), "+v"(wioff));

        const int t = isL1 ? (k - 2) : k;

        // ================= CRITICAL phase =================
        if (t >= 0 && t < TT) {
            float4 hp4[4];
            const float* hpv = (t > 0)
                ? (isL1 ? out + (size_t)(t - 1) * HH : ring + (size_t)((t - 1) & 7) * HH)
                : zbuf;
            load64B_llc(hp4, hpv + col);

            float acc0, acc1, acc2, acc3, acc4, acc5, acc6, acc7;
            #define DOTW(r) { float a = gxp##r; \
                const float4* wp = (const float4*)(ldsw + loff + (r) * 1024); \
                fma4(a, wp[0],   hp4[0]); fma4(a, wp[64],  hp4[1]); \
                fma4(a, wp[128], hp4[2]); fma4(a, wp[192], hp4[3]); \
                acc##r = a; }
            FOR_R(DOTW)

            #define REDW(m) \
                acc0 += __shfl_xor(acc0, m, 64); acc1 += __shfl_xor(acc1, m, 64); \
                acc2 += __shfl_xor(acc2, m, 64); acc3 += __shfl_xor(acc3, m, 64); \
                acc4 += __shfl_xor(acc4, m, 64); acc5 += __shfl_xor(acc5, m, 64); \
                acc6 += __shfl_xor(acc6, m, 64); acc7 += __shfl_xor(acc7, m, 64);
            REDW(1) REDW(2) REDW(4) REDW(8) REDW(16) REDW(32)

            // gates (PyTorch order i,f,g,o); bias added post-reduce
            const float gi0 = fsigmoid(acc0 + B0), gf0 = fsigmoid(acc1 + B1);
            const float gg0 = ftanh(acc2 + B2),    go0 = fsigmoid(acc3 + B3);
            c0v = gf0 * c0v + gi0 * gg0;
            const float h0 = go0 * ftanh(c0v);
            const float gi1 = fsigmoid(acc4 + B4), gf1 = fsigmoid(acc5 + B5);
            const float gg1 = ftanh(acc6 + B6),    go1 = fsigmoid(acc7 + B7);
            c1v = gf1 * c1v + gi1 * gg1;
            const float h1v = go1 * ftanh(c1v);

            if (lane == 0) {
                float2 hv = make_float2(h0, h1v);   // jbase, jbase+1 (jbase even)
                unsigned long long bits;
                __builtin_memcpy(&bits, &hv, 8);
                float* dstf = isL1 ? (out  + (size_t)t * HH + jbase)
                                   : (ring + (size_t)(t & 7) * HH + jbase);
                __hip_atomic_store((unsigned long long*)dstf, bits,
                                   __ATOMIC_RELAXED, __HIP_MEMORY_SCOPE_AGENT);
            }
        }

        __syncthreads();   // all 4 waves drain their h stores (vmcnt before s_barrier)

        if (k <= TT) {
            // ================= ARRIVE: plain per-WG epoch store ==============
            if (tid == 0) {
                asm volatile("s_waitcnt vmcnt(0)" ::: "memory");
                __hip_atomic_store(&slots[wg], (unsigned)(k + 1),
                                   __ATOMIC_RELAXED, __HIP_MEMORY_SCOPE_AGENT);
            }

            // ================= SLACK phase (overlaps arrival propagation) =====
            {
                const int tn = t + 1;
                if (tn >= 0 && tn < TT) {
                    float4 iv4[4];
                    if (!isL1) {
                        const float4* p = (const float4*)(x + (size_t)tn * HH + col);
                        iv4[0] = p[0]; iv4[1] = p[1]; iv4[2] = p[2]; iv4[3] = p[3];
                    } else {
                        // h1[tn]: published by L0 at its step tn, guaranteed by
                        // the previous barrier's slots_L0 >= k
                        load64B_llc(iv4, ring + (size_t)(tn & 7) * HH + col);
                    }
                    FOR_R(GXR)
                }
            }
            // anchor gx results so the slack work cannot sink past the poll
            asm volatile("" : "+v"(gxp0), "+v"(gxp1), "+v"(gxp2), "+v"(gxp3),
                             "+v"(gxp4), "+v"(gxp5), "+v"(gxp6), "+v"(gxp7));

            // ================= POLL: per-layer thresholds (thin) =============
            const unsigned tgt = (unsigned)(k + 1);
            const unsigned lag = (k >= 5) ? (unsigned)(k - 4) : 0u;
            if (!isL1)  slot_barrier_wait2(slots, tgt, lag);   // L0: loose on L1
            else        slot_barrier_wait2(slots, tgt, tgt);   // L1: full
        }
    }
}

extern "C" void kernel_launch(void* const* d_in, const int* in_sizes, int n_in,
                              void* d_out, int out_size, void* d_ws, size_t ws_size,
                              hipStream_t stream) {
    (void)in_sizes; (void)n_in; (void)out_size; (void)ws_size;
    const float* x    = (const float*)d_in[0];
    const float* wih0 = (const float*)d_in[1];
    const float* whh0 = (const float*)d_in[2];
    const float* bih0 = (const float*)d_in[3];
    const float* bhh0 = (const float*)d_in[4];
    const float* wih1 = (const float*)d_in[5];
    const float* whh1 = (const float*)d_in[6];
    const float* bih1 = (const float*)d_in[7];
    const float* bhh1 = (const float*)d_in[8];
    float* out = (float*)d_out;

    // ws layout: [0,1024) slots (256 x 4B) | [4096,8192) zbuf |
    //            [8192,40960) ring (8 slots x 4 KB)
    unsigned* slots = (unsigned*)d_ws;
    float*    zbuf  = (float*)((char*)d_ws + 4096);
    float*    ring  = (float*)((char*)d_ws + 8192);

    // allow 128 KB dynamic LDS (160 KB available per CU on gfx950)
    (void)hipFuncSetAttribute((const void*)lstm2_persistent,
                              hipFuncAttributeMaxDynamicSharedMemorySize, LDS_BYTES);

    // zero slots + zbuf + ring every call (stream-ordered, graph-capturable)
    (void)hipMemsetAsync(d_ws, 0, 40960, stream);

    hipLaunchKernelGGL(lstm2_persistent, dim3(NWG), dim3(256), LDS_BYTES, stream,
                       x, wih0, whh0, bih0, bhh0,
                       wih1, whh1, bih1, bhh1, out, ring, zbuf, slots);
}

// Round 18
// 19407.054 us; speedup vs baseline: 5.1181x; 1.0143x over previous
//
#include <hip/hip_runtime.h>

#define HH 1024
#define TT 4096
#define NWG 256
#define NWG_PER_LAYER 128
#define JS_PER_WG 8     // 1024 / 128
#define JS_PER_WAVE 2   // 8 j's / 4 waves
#define LDS_BYTES 131072  // 4 waves * 8 rows * 1024 floats * 4 B (w_hh tile)

__device__ __forceinline__ float fsigmoid(float x) {
    return 1.0f / (1.0f + __expf(-x));
}
__device__ __forceinline__ float ftanh(float x) {
    float ax = fabsf(x);
    float e = __expf(-2.0f * ax);
    float t = (1.0f - e) / (1.0f + e);
    return copysignf(t, x);
}
__device__ __forceinline__ void fma4(float& a, const float4 w, const float4 v) {
    a = fmaf(w.x, v.x, a);
    a = fmaf(w.y, v.y, a);
    a = fmaf(w.z, v.z, a);
    a = fmaf(w.w, v.w, a);
}

// Dual LLC-coherent 64B load, ONE round-trip: 8 pipelined dwordx4 sc0 sc1
// with a single vmcnt. Round-18 change: fuses the recurrence-h load and the
// next-step gx-input load (r13 issued them in separate phases = 2 serialized
// RTs on L1's path; both are barrier-guaranteed visible at step start).
__device__ __forceinline__ void load2x64B_llc(float4 a[4], float4 b[4],
                                              const float* pa, const float* pb) {
    asm volatile(
        "global_load_dwordx4 %0, %8, off sc0 sc1\n\t"
        "global_load_dwordx4 %1, %8, off offset:16 sc0 sc1\n\t"
        "global_load_dwordx4 %2, %8, off offset:32 sc0 sc1\n\t"
        "global_load_dwordx4 %3, %8, off offset:48 sc0 sc1\n\t"
        "global_load_dwordx4 %4, %9, off sc0 sc1\n\t"
        "global_load_dwordx4 %5, %9, off offset:16 sc0 sc1\n\t"
        "global_load_dwordx4 %6, %9, off offset:32 sc0 sc1\n\t"
        "global_load_dwordx4 %7, %9, off offset:48 sc0 sc1\n\t"
        "s_waitcnt vmcnt(0)"
        : "=&v"(a[0]), "=&v"(a[1]), "=&v"(a[2]), "=&v"(a[3]),
          "=&v"(b[0]), "=&v"(b[1]), "=&v"(b[2]), "=&v"(b[3])
        : "v"(pa), "v"(pb)
        : "memory");
}

// r13-proven thin slot barrier: lane l reads slots[4l..4l+3] with one dwordx4
// sc0 sc1 (64 lanes = all 256 slots = one LLC RT per attempt). r15/r16 law:
// poll attempts stay thin (<=16B/lane); data loads are issued once, fused at
// step start.
__device__ __forceinline__ void slot_barrier_wait(const unsigned* slots, unsigned tgt) {
    const unsigned* p = slots + 4 * (threadIdx.x & 63);
    for (;;) {
        uint4 v;
        asm volatile(
            "global_load_dwordx4 %0, %1, off sc0 sc1\n\t"
            "s_waitcnt vmcnt(0)"
            : "=&v"(v) : "v"(p) : "memory");
        const unsigned m = min(min(v.x, v.y), min(v.z, v.w));
        if (__all(m >= tgt)) break;
        __builtin_amdgcn_s_sleep(1);
    }
}

#define FOR_R(F) F(0) F(1) F(2) F(3) F(4) F(5) F(6) F(7)

// Persistent 2-layer LSTM = round-13 skeleton + fused step-start dual load.
// WGs [0,128): layer 0 (t = k). WGs [128,256): layer 1 (t = k-2, skew 2).
// Per step: DUAL LOAD {recurrence h[t-1] + next gx input, 1 RT} -> CRITICAL
// {w_hh GEMV (LDS) -> reduce -> +bias -> gates -> store h} -> syncthreads ->
// ARRIVE (tid0: slot[wg]=k+1, plain store) -> SLACK {gx[t+1] = w_ih @ iv,
// pure FMA on pre-loaded registers} -> POLL (thin, full coupling).
// Visibility audit: L1's iv = h1[k-1] published by L0 at step k-1, covered by
// barrier k-1 (which completed before step k began); ring slot (k-1)&3 next
// overwritten at L0 step k+3, gated by barrier k+2 -> needs L1 >= k+3. Safe.
//   w_hh: 128 KB LDS [wave][row][q][lane] (conflict-free ds_read_b128)
//   w_ih: streamed from global (L2-resident) every step, in slack
//   h1: plain ring [4][1024]; h2 recurrence reads `out` directly.
__global__ __launch_bounds__(256, 1) void lstm2_persistent(
    const float* __restrict__ x,
    const float* __restrict__ wih0, const float* __restrict__ whh0,
    const float* __restrict__ bih0, const float* __restrict__ bhh0,
    const float* __restrict__ wih1, const float* __restrict__ whh1,
    const float* __restrict__ bih1, const float* __restrict__ bhh1,
    float* __restrict__ out,     // [T][H]  h2 (output + h2 recurrence buffer)
    float* __restrict__ ring,    // [4][H]  h1 ring (layer0 <-> layer1)
    const float* __restrict__ zbuf,   // [H] zeros (h[-1] / inactive-phase fallback)
    unsigned* __restrict__ slots)     // 256 per-WG epoch slots (zeroed)
{
    extern __shared__ float ldsw[];   // w_hh tile, 128 KB

    const int wg   = blockIdx.x;
    const int tid  = threadIdx.x;
    const int wave = tid >> 6;
    const int lane = tid & 63;
    const bool isL1 = (wg >= NWG_PER_LAYER);
    const int wgl   = isL1 ? (wg - NWG_PER_LAYER) : wg;
    const int jbase = wgl * JS_PER_WG + wave * JS_PER_WAVE;
    const int col   = lane * 16;   // this lane's 16-elem chunk of the 1024-vector

    const float* wih = isL1 ? wih1 : wih0;
    const float* whh = isL1 ? whh1 : whh0;
    const float* bih = isL1 ? bih1 : bih0;
    const float* bhh = isL1 ? bhh1 : bhh0;

    // ---- stage w_hh into LDS: float offset = wave*8192 + r*1024 + q*256 + lane*4
    #pragma unroll
    for (int r = 0; r < 8; ++r) {
        const int row = (r & 3) * HH + (jbase + (r >> 2));
        const float4* p  = (const float4*)(whh + (size_t)row * HH + col);
        float*       wb = ldsw + wave * 8192 + r * 1024 + lane * 4;
        #pragma unroll
        for (int q = 0; q < 4; ++q)
            *(float4*)(wb + q * 256) = p[q];
    }

    // ---- bias (applied AFTER the butterfly reduce, uniform across lanes) ----
    #define DECLB(r) float B##r; { const int row = ((r)&3)*HH + (jbase + ((r)>>2)); \
                                   B##r = bih[row] + bhh[row]; }
    FOR_R(DECLB)

    // gx per-lane partials, carried in registers across the step boundary
    #define DECLG(r) float gxp##r = 0.0f;
    FOR_R(DECLG)

    float c0v = 0.0f, c1v = 0.0f;
    int loff  = wave * 8192 + lane * 4;  // LDS float offset (pinned per iter)
    int wioff = 0;                       // global w_ih offset (pinned per iter)

    // streamed input-GEMV partial: gxp_r = w_ih[rows(r)][col..col+16) @ iv
    // (NO bias here -- per-lane partials get summed 64x by the reduce)
    #define GXR(r) { \
        const int row = ((r) & 3) * HH + (jbase + ((r) >> 2)); \
        const float4* wp = (const float4*)(wih + (size_t)row * HH + col + wioff); \
        float4 w0 = wp[0], w1 = wp[1], w2 = wp[2], w3 = wp[3]; \
        float a = 0.0f; \
        fma4(a, w0, iv4[0]); fma4(a, w1, iv4[1]); \
        fma4(a, w2, iv4[2]); fma4(a, w3, iv4[3]); \
        gxp##r = a; }

    // ---- prologue: L0 needs gx[0] before the first step ----
    if (!isL1) {
        float4 iv4[4];
        const float4* p = (const float4*)(x + col);
        iv4[0] = p[0]; iv4[1] = p[1]; iv4[2] = p[2]; iv4[3] = p[3];
        FOR_R(GXR)
    }

    __syncthreads();   // LDS w_hh tile ready

    for (int k = 0; k <= TT + 1; ++k) {
        // per-iteration pins: block LICM of the (address-invariant) LDS w_hh
        // reads and global w_ih loads into spillable long-lived registers
        asm volatile("" : "+v"(loff), "+v"(wioff));

        const int t  = isL1 ? (k - 2) : k;
        const int tn = t + 1;

        // ============ fused step-start dual load (1 LLC RT) ============
        // hp4: recurrence h[t-1] (zbuf when t==0 or critical inactive)
        // iv4: next gx input -- L0: x[tn]; L1: h1[tn] (zbuf when inactive)
        float4 hp4[4], iv4[4];
        {
            const float* hpv = (t > 0 && t < TT)
                ? (isL1 ? out + (size_t)(t - 1) * HH
                        : ring + (size_t)((t - 1) & 3) * HH)
                : zbuf;
            const float* ivp = (tn >= 0 && tn < TT)
                ? (isL1 ? ring + (size_t)(tn & 3) * HH
                        : x + (size_t)tn * HH)
                : zbuf;
            load2x64B_llc(hp4, iv4, hpv + col, ivp + col);
        }

        // ================= CRITICAL phase =================
        if (t >= 0 && t < TT) {
            float acc0, acc1, acc2, acc3, acc4, acc5, acc6, acc7;
            #define DOTW(r) { float a = gxp##r; \
                const float4* wp = (const float4*)(ldsw + loff + (r) * 1024); \
                fma4(a, wp[0],   hp4[0]); fma4(a, wp[64],  hp4[1]); \
                fma4(a, wp[128], hp4[2]); fma4(a, wp[192], hp4[3]); \
                acc##r = a; }
            FOR_R(DOTW)

            #define REDW(m) \
                acc0 += __shfl_xor(acc0, m, 64); acc1 += __shfl_xor(acc1, m, 64); \
                acc2 += __shfl_xor(acc2, m, 64); acc3 += __shfl_xor(acc3, m, 64); \
                acc4 += __shfl_xor(acc4, m, 64); acc5 += __shfl_xor(acc5, m, 64); \
                acc6 += __shfl_xor(acc6, m, 64); acc7 += __shfl_xor(acc7, m, 64);
            REDW(1) REDW(2) REDW(4) REDW(8) REDW(16) REDW(32)

            // gates (PyTorch order i,f,g,o); bias added post-reduce
            const float gi0 = fsigmoid(acc0 + B0), gf0 = fsigmoid(acc1 + B1);
            const float gg0 = ftanh(acc2 + B2),    go0 = fsigmoid(acc3 + B3);
            c0v = gf0 * c0v + gi0 * gg0;
            const float h0 = go0 * ftanh(c0v);
            const float gi1 = fsigmoid(acc4 + B4), gf1 = fsigmoid(acc5 + B5);
            const float gg1 = ftanh(acc6 + B6),    go1 = fsigmoid(acc7 + B7);
            c1v = gf1 * c1v + gi1 * gg1;
            const float h1v = go1 * ftanh(c1v);

            if (lane == 0) {
                float2 hv = make_float2(h0, h1v);   // jbase, jbase+1 (jbase even)
                unsigned long long bits;
                __builtin_memcpy(&bits, &hv, 8);
                float* dstf = isL1 ? (out  + (size_t)t * HH + jbase)
                                   : (ring + (size_t)(t & 3) * HH + jbase);
                __hip_atomic_store((unsigned long long*)dstf, bits,
                                   __ATOMIC_RELAXED, __HIP_MEMORY_SCOPE_AGENT);
            }
        }

        __syncthreads();   // all 4 waves drain their h stores (vmcnt before s_barrier)

        if (k <= TT) {
            // ================= ARRIVE: plain per-WG epoch store ==============
            if (tid == 0) {
                asm volatile("s_waitcnt vmcnt(0)" ::: "memory");
                __hip_atomic_store(&slots[wg], (unsigned)(k + 1),
                                   __ATOMIC_RELAXED, __HIP_MEMORY_SCOPE_AGENT);
            }

            // ====== SLACK: gx for next timestep (pure register FMAs) =========
            if (tn >= 0 && tn < TT) {
                FOR_R(GXR)
            }
            // anchor gx results so the slack work cannot sink past the poll
            asm volatile("" : "+v"(gxp0), "+v"(gxp1), "+v"(gxp2), "+v"(gxp3),
                             "+v"(gxp4), "+v"(gxp5), "+v"(gxp6), "+v"(gxp7));

            // ================= POLL: all 256 slots >= k+1 (thin) =============
            slot_barrier_wait(slots, (unsigned)(k + 1));
        }
    }
}

extern "C" void kernel_launch(void* const* d_in, const int* in_sizes, int n_in,
                              void* d_out, int out_size, void* d_ws, size_t ws_size,
                              hipStream_t stream) {
    (void)in_sizes; (void)n_in; (void)out_size; (void)ws_size;
    const float* x    = (const float*)d_in[0];
    const float* wih0 = (const float*)d_in[1];
    const float* whh0 = (const float*)d_in[2];
    const float* bih0 = (const float*)d_in[3];
    const float* bhh0 = (const float*)d_in[4];
    const float* wih1 = (const float*)d_in[5];
    const float* whh1 = (const float*)d_in[6];
    const float* bih1 = (const float*)d_in[7];
    const float* bhh1 = (const float*)d_in[8];
    float* out = (float*)d_out;

    // ws layout: [0,1024) slots (256 x 4B) | [4096,8192) zbuf |
    //            [8192,24576) ring (4 slots x 4 KB)
    unsigned* slots = (unsigned*)d_ws;
    float*    zbuf  = (float*)((char*)d_ws + 4096);
    float*    ring  = (float*)((char*)d_ws + 8192);

    // allow 128 KB dynamic LDS (160 KB available per CU on gfx950)
    (void)hipFuncSetAttribute((const void*)lstm2_persistent,
                              hipFuncAttributeMaxDynamicSharedMemorySize, LDS_BYTES);

    // zero slots + zbuf + ring every call (stream-ordered, graph-capturable)
    (void)hipMemsetAsync(d_ws, 0, 24576, stream);

    hipLaunchKernelGGL(lstm2_persistent, dim3(NWG), dim3(256), LDS_BYTES, stream,
                       x, wih0, whh0, bih0, bhh0,
                       wih1, whh1, bih1, bhh1, out, ring, zbuf, slots);
}